// Round 4
// baseline (163.531 us; speedup 1.0000x reference)
//
#include <hip/hip_runtime.h>
#include <hip/hip_bf16.h>

#define NE 100000
#define NK 16
#define ND 128
#define NTILES 6250   // NE / 16

typedef __bf16 bf16_t;
typedef bf16_t bf16x8 __attribute__((ext_vector_type(8)));
typedef bf16_t bf16x4 __attribute__((ext_vector_type(4)));
typedef float f32x4 __attribute__((ext_vector_type(4)));
typedef unsigned short u16;

__device__ __forceinline__ u16 f2bf(float f) {
  bf16_t h = (bf16_t)f;
  return __builtin_bit_cast(u16, h);
}

// ---------------------------------------------------------------------------
// k_prep: bf16-convert weights; fold Wp = Um@mW2, bp = ub1 + Um@mb2.
// ---------------------------------------------------------------------------
__global__ void k_prep(const float* __restrict__ mW1, const float* __restrict__ uW1,
                       const float* __restrict__ uW2, const float* __restrict__ mW2,
                       const float* __restrict__ ub1, const float* __restrict__ mb2,
                       u16* __restrict__ Wi_b, u16* __restrict__ Wj_b,
                       u16* __restrict__ Ui_b, u16* __restrict__ Wp_b,
                       u16* __restrict__ W2_b, float* __restrict__ bp)
{
  const int o = blockIdx.x, t = threadIdx.x;
  Wi_b[o * ND + t] = f2bf(mW1[o * 256 + t]);
  Wj_b[o * ND + t] = f2bf(mW1[o * 256 + 128 + t]);
  Ui_b[o * ND + t] = f2bf(uW1[o * 256 + t]);
  W2_b[o * ND + t] = f2bf(uW2[o * ND + t]);
  float acc = 0.f;
  for (int p = 0; p < 128; ++p)
    acc += uW1[o * 256 + 128 + p] * mW2[p * 128 + t];
  Wp_b[o * ND + t] = f2bf(acc);
  if (t == 0) {
    float b = ub1[o];
    for (int p = 0; p < 128; ++p) b += uW1[o * 256 + 128 + p] * mb2[p];
    bp[o] = b;
  }
}

// ---------------------------------------------------------------------------
// k1: S = X@Wi^T + mb1 (bf16), Z = X@Wj^T (bf16), T1 = X@Ui^T + bp (bf16,
// stored in out rows at u16-stride 256). Wave w keeps Wi/Wj/Ui nt-tiles
// {2w,2w+1} register-resident; block grid-strides over edge tiles with
// next-tile X prefetch. grid=2048: ~3 tiles/block, cold-start overlapped.
// ---------------------------------------------------------------------------
__global__ __launch_bounds__(256) void k1_szt(
    const float* __restrict__ X, const u16* __restrict__ Wi_b,
    const u16* __restrict__ Wj_b, const u16* __restrict__ Ui_b,
    const float* __restrict__ mb1, const float* __restrict__ bp,
    u16* __restrict__ Sb, u16* __restrict__ Zb, u16* __restrict__ T1)
{
  const int tid = threadIdx.x, wid = tid >> 6, lane = tid & 63;
  const int r = lane & 15, q = lane >> 4;

  bf16x8 wiF[2][4], wjF[2][4], uiF[2][4];
  f32x4 mbF[2], bpF[2];
#pragma unroll
  for (int j = 0; j < 2; ++j) {
    const int row = (2 * wid + j) * 16 + r;
#pragma unroll
    for (int kk = 0; kk < 4; ++kk) {
      wiF[j][kk] = *(const bf16x8*)(Wi_b + row * ND + kk * 32 + q * 8);
      wjF[j][kk] = *(const bf16x8*)(Wj_b + row * ND + kk * 32 + q * 8);
      uiF[j][kk] = *(const bf16x8*)(Ui_b + row * ND + kk * 32 + q * 8);
    }
    mbF[j] = *(const f32x4*)(mb1 + (2 * wid + j) * 16 + q * 4);
    bpF[j] = *(const f32x4*)(bp  + (2 * wid + j) * 16 + q * 4);
  }

  const long stride = gridDim.x;
  long t = blockIdx.x;
  if (t >= NTILES) return;

  f32x4 xraw[8];
  auto loadx = [&](long tt) {
    const float* xp = X + (tt * 16 + r) * ND + q * 8;
#pragma unroll
    for (int kk = 0; kk < 4; ++kk) {
      xraw[2 * kk]     = *(const f32x4*)(xp + kk * 32);
      xraw[2 * kk + 1] = *(const f32x4*)(xp + kk * 32 + 4);
    }
  };
  loadx(t);

  for (; t < NTILES; t += stride) {
    bf16x8 xf[4];
#pragma unroll
    for (int kk = 0; kk < 4; ++kk) {
      bf16x8 v;
#pragma unroll
      for (int i = 0; i < 4; ++i) {
        v[i]     = (bf16_t)xraw[2 * kk][i];
        v[i + 4] = (bf16_t)xraw[2 * kk + 1][i];
      }
      xf[kk] = v;
    }
    const long tn = t + stride;
    if (tn < NTILES) loadx(tn);   // prefetch next tile while MFMAs run

    const long rowS = (t * 16 + r) * ND;
    const long rowT = (t * 16 + r) * 256;
#pragma unroll
    for (int j = 0; j < 2; ++j) {
      f32x4 aS = {0.f, 0.f, 0.f, 0.f};
      f32x4 aZ = {0.f, 0.f, 0.f, 0.f};
      f32x4 aT = {0.f, 0.f, 0.f, 0.f};
#pragma unroll
      for (int kk = 0; kk < 4; ++kk) {
        aS = __builtin_amdgcn_mfma_f32_16x16x32_bf16(wiF[j][kk], xf[kk], aS, 0, 0, 0);
        aZ = __builtin_amdgcn_mfma_f32_16x16x32_bf16(wjF[j][kk], xf[kk], aZ, 0, 0, 0);
        aT = __builtin_amdgcn_mfma_f32_16x16x32_bf16(uiF[j][kk], xf[kk], aT, 0, 0, 0);
      }
      const int cb = (2 * wid + j) * 16 + q * 4;
      bf16x4 pS, pZ, pT;
#pragma unroll
      for (int i = 0; i < 4; ++i) {
        pS[i] = (bf16_t)(aS[i] + mbF[j][i]);
        pZ[i] = (bf16_t)aZ[i];
        pT[i] = (bf16_t)(aT[i] + bpF[j][i]);
      }
      *(bf16x4*)(Sb + rowS + cb) = pS;
      *(bf16x4*)(Zb + rowS + cb) = pZ;
      *(bf16x4*)(T1 + rowT + cb) = pT;
    }
  }
}

// ---------------------------------------------------------------------------
// k23: fused gather + both update GEMMs. One block per 16-edge tile.
// Phase A (gather): wave w handles edges {4w..4w+3}. Lane = (g,i), g=lane>>4,
//   i=lane&15: group g gathers 16B slices (dims 8i..8i+7) of neighbor rows
//   n[4t+g]; relu(S+Z) accumulated in-lane, then shfl_xor butterfly over
//   groups; hbar -> swizzled LDS tile.
// Phase B: u = relu(T1 + hbar@Wp^T); out = u@uW2^T + ub2, weights
//   register-resident (wave w owns channel tiles {2w,2w+1}); u exchanged
//   via a second swizzled LDS tile. Swizzle: byte_in_row ^= (row&15)<<4
//   (same involution on write and read; 8 words/bank floor on b128 reads).
// ---------------------------------------------------------------------------
__global__ __launch_bounds__(256) void k23_out(
    const u16* __restrict__ Zb, const u16* __restrict__ Sb,
    const int* __restrict__ adj, const u16* __restrict__ T1,
    const u16* __restrict__ Wp_b, const u16* __restrict__ W2_b,
    const float* __restrict__ ub2, float* __restrict__ out)
{
  __shared__ u16 hbuf[16 * ND];
  __shared__ u16 ubuf[16 * ND];
  const int tid = threadIdx.x, wid = tid >> 6, lane = tid & 63;
  const int r = lane & 15, q = lane >> 4;   // frag coords
  const int i16 = r, g = q;                 // gather coords (same split)

  // register-resident weights for phase B
  bf16x8 wpF[2][4], w2F[2][4];
  f32x4 ubF[2];
#pragma unroll
  for (int j = 0; j < 2; ++j) {
    const int row = (2 * wid + j) * 16 + r;
#pragma unroll
    for (int kk = 0; kk < 4; ++kk) {
      wpF[j][kk] = *(const bf16x8*)(Wp_b + row * ND + kk * 32 + q * 8);
      w2F[j][kk] = *(const bf16x8*)(W2_b + row * ND + kk * 32 + q * 8);
    }
    ubF[j] = *(const f32x4*)(ub2 + (2 * wid + j) * 16 + q * 4);
  }

  const long e0 = (long)blockIdx.x * 16;

  // ---- Phase A: gather ----
#pragma unroll
  for (int ee = 0; ee < 4; ++ee) {
    const int erow = wid * 4 + ee;
    const long e = e0 + erow;
    const int* ar = adj + e * NK;
    const int n0 = ar[g], n1 = ar[g + 4], n2 = ar[g + 8], n3 = ar[g + 12];
    const bf16x8 sv = *(const bf16x8*)(Sb + e * ND + i16 * 8);
    const bf16x8 z0 = *(const bf16x8*)(Zb + (long)n0 * ND + i16 * 8);
    const bf16x8 z1 = *(const bf16x8*)(Zb + (long)n1 * ND + i16 * 8);
    const bf16x8 z2 = *(const bf16x8*)(Zb + (long)n2 * ND + i16 * 8);
    const bf16x8 z3 = *(const bf16x8*)(Zb + (long)n3 * ND + i16 * 8);
    float acc[8];
#pragma unroll
    for (int d = 0; d < 8; ++d) {
      const float s = (float)sv[d];
      acc[d] = fmaxf(s + (float)z0[d], 0.f) + fmaxf(s + (float)z1[d], 0.f)
             + fmaxf(s + (float)z2[d], 0.f) + fmaxf(s + (float)z3[d], 0.f);
    }
#pragma unroll
    for (int d = 0; d < 8; ++d) {
      acc[d] += __shfl_xor(acc[d], 16);
      acc[d] += __shfl_xor(acc[d], 32);
    }
    if (g == 0) {
      bf16x8 hv;
#pragma unroll
      for (int d = 0; d < 8; ++d) hv[d] = (bf16_t)(acc[d] * 0.0625f);
      const int byteoff = erow * 256 + ((i16 * 16) ^ (erow << 4));
      *(bf16x8*)((char*)hbuf + byteoff) = hv;
    }
  }
  __syncthreads();

  // ---- Phase B: u = relu(T1 + hbar@Wp^T) ----
  bf16x8 hf[4];
#pragma unroll
  for (int kk = 0; kk < 4; ++kk) {
    const int byteoff = r * 256 + ((kk * 64 + q * 16) ^ (r << 4));
    hf[kk] = *(const bf16x8*)((const char*)hbuf + byteoff);
  }

  f32x4 acc2[2];
#pragma unroll
  for (int j = 0; j < 2; ++j) {
    const bf16x4 tv = *(const bf16x4*)(T1 + (e0 + r) * 256 + (2 * wid + j) * 16 + q * 4);
#pragma unroll
    for (int i = 0; i < 4; ++i) acc2[j][i] = (float)tv[i];
  }
#pragma unroll
  for (int j = 0; j < 2; ++j)
#pragma unroll
    for (int kk = 0; kk < 4; ++kk)
      acc2[j] = __builtin_amdgcn_mfma_f32_16x16x32_bf16(wpF[j][kk], hf[kk], acc2[j], 0, 0, 0);

#pragma unroll
  for (int j = 0; j < 2; ++j) {
    bf16x4 u;
#pragma unroll
    for (int i = 0; i < 4; ++i) u[i] = (bf16_t)fmaxf(acc2[j][i], 0.f);
    const int byteoff = r * 256 + ((((2 * wid + j) * 32) + q * 8) ^ (r << 4));
    *(bf16x4*)((char*)ubuf + byteoff) = u;
  }
  __syncthreads();

  // ---- out = u @ uW2^T + ub2 ----
  bf16x8 uf[4];
#pragma unroll
  for (int kk = 0; kk < 4; ++kk) {
    const int byteoff = r * 256 + ((kk * 64 + q * 16) ^ (r << 4));
    uf[kk] = *(const bf16x8*)((const char*)ubuf + byteoff);
  }
#pragma unroll
  for (int j = 0; j < 2; ++j) {
    f32x4 o = {0.f, 0.f, 0.f, 0.f};
#pragma unroll
    for (int kk = 0; kk < 4; ++kk)
      o = __builtin_amdgcn_mfma_f32_16x16x32_bf16(w2F[j][kk], uf[kk], o, 0, 0, 0);
#pragma unroll
    for (int i = 0; i < 4; ++i) o[i] += ubF[j][i];
    *(f32x4*)(out + (e0 + r) * ND + (2 * wid + j) * 16 + q * 4) = o;
  }
}

extern "C" void kernel_launch(void* const* d_in, const int* in_sizes, int n_in,
                              void* d_out, int out_size, void* d_ws, size_t ws_size,
                              hipStream_t stream)
{
  (void)in_sizes; (void)n_in; (void)out_size; (void)ws_size;
  const float* X   = (const float*)d_in[0];
  const int*   adj = (const int*)d_in[1];
  const float* mW1 = (const float*)d_in[2];
  const float* mb1 = (const float*)d_in[3];
  const float* mW2 = (const float*)d_in[4];
  const float* mb2 = (const float*)d_in[5];
  const float* uW1 = (const float*)d_in[6];
  const float* ub1 = (const float*)d_in[7];
  const float* uW2 = (const float*)d_in[8];
  const float* ub2 = (const float*)d_in[9];
  float* out = (float*)d_out;

  u16* ws16 = (u16*)d_ws;
  u16* Sb   = ws16;                              // E*D bf16
  u16* Zb   = Sb + (size_t)NE * ND;              // E*D bf16
  u16* Wi_b = Zb + (size_t)NE * ND;              // 128*128 bf16 each:
  u16* Wj_b = Wi_b + 128 * 128;
  u16* Ui_b = Wj_b + 128 * 128;
  u16* Wp_b = Ui_b + 128 * 128;
  u16* W2_b = Wp_b + 128 * 128;
  float* bp = (float*)(W2_b + 128 * 128);        // 128 f32
  u16* T1   = (u16*)d_out;                       // bf16 T1, stride 256, in out rows

  k_prep<<<128, 128, 0, stream>>>(mW1, uW1, uW2, mW2, ub1, mb2,
                                  Wi_b, Wj_b, Ui_b, Wp_b, W2_b, bp);

  k1_szt<<<2048, 256, 0, stream>>>(X, Wi_b, Wj_b, Ui_b, mb1, bp, Sb, Zb, T1);

  k23_out<<<NTILES, 256, 0, stream>>>(Zb, Sb, adj, T1, Wp_b, W2_b, ub2, out);
}

// Round 5
// 157.739 us; speedup vs baseline: 1.0367x; 1.0367x over previous
//
#include <hip/hip_runtime.h>
#include <hip/hip_bf16.h>

#define NE 100000
#define NK 16
#define ND 128
#define NTILES 6250   // NE / 16

typedef __bf16 bf16_t;
typedef bf16_t bf16x8 __attribute__((ext_vector_type(8)));
typedef bf16_t bf16x4 __attribute__((ext_vector_type(4)));
typedef float f32x4 __attribute__((ext_vector_type(4)));
typedef unsigned short u16;

__device__ __forceinline__ u16 f2bf(float f) {
  bf16_t h = (bf16_t)f;
  return __builtin_bit_cast(u16, h);
}
__device__ __forceinline__ float bf2f(unsigned int bits) {
  return __builtin_bit_cast(float, bits << 16);
}

// ---------------------------------------------------------------------------
// k_prep: bf16-convert weights; fold Wp = Um@mW2, bp = ub1 + Um@mb2.
// ---------------------------------------------------------------------------
__global__ void k_prep(const float* __restrict__ mW1, const float* __restrict__ uW1,
                       const float* __restrict__ uW2, const float* __restrict__ mW2,
                       const float* __restrict__ ub1, const float* __restrict__ mb2,
                       u16* __restrict__ Wi_b, u16* __restrict__ Wj_b,
                       u16* __restrict__ Ui_b, u16* __restrict__ Wp_b,
                       u16* __restrict__ W2_b, float* __restrict__ bp)
{
  const int o = blockIdx.x, t = threadIdx.x;
  Wi_b[o * ND + t] = f2bf(mW1[o * 256 + t]);
  Wj_b[o * ND + t] = f2bf(mW1[o * 256 + 128 + t]);
  Ui_b[o * ND + t] = f2bf(uW1[o * 256 + t]);
  W2_b[o * ND + t] = f2bf(uW2[o * ND + t]);
  float acc = 0.f;
  for (int p = 0; p < 128; ++p)
    acc += uW1[o * 256 + 128 + p] * mW2[p * 128 + t];
  Wp_b[o * ND + t] = f2bf(acc);
  if (t == 0) {
    float b = ub1[o];
    for (int p = 0; p < 128; ++p) b += uW1[o * 256 + 128 + p] * mb2[p];
    bp[o] = b;
  }
}

// ---------------------------------------------------------------------------
// k1: S = X@Wi^T + mb1, Z = X@Wj^T, T1 = X@Ui^T + bp (all bf16; T1 stored in
// out rows at u16-stride 256). Wave w keeps Wi/Wj/Ui tiles {2w,2w+1}
// register-resident; grid-stride over tiles with next-tile X prefetch.
// Epilogue: accs -> swizzled LDS tile -> one coalesced 16B-row-chunk store
// per thread per output (full-line writes; was 16x32B scatter per instr).
// ---------------------------------------------------------------------------
__global__ __launch_bounds__(256) void k1_szt(
    const float* __restrict__ X, const u16* __restrict__ Wi_b,
    const u16* __restrict__ Wj_b, const u16* __restrict__ Ui_b,
    const float* __restrict__ mb1, const float* __restrict__ bp,
    u16* __restrict__ Sb, u16* __restrict__ Zb, u16* __restrict__ T1)
{
  __shared__ u16 st[2][3][16 * ND];   // [buf][S,Z,T][edge][ch], 24 KB
  const int tid = threadIdx.x, wid = tid >> 6, lane = tid & 63;
  const int r = lane & 15, q = lane >> 4;

  bf16x8 wiF[2][4], wjF[2][4], uiF[2][4];
  f32x4 mbF[2], bpF[2];
#pragma unroll
  for (int j = 0; j < 2; ++j) {
    const int row = (2 * wid + j) * 16 + r;
#pragma unroll
    for (int kk = 0; kk < 4; ++kk) {
      wiF[j][kk] = *(const bf16x8*)(Wi_b + row * ND + kk * 32 + q * 8);
      wjF[j][kk] = *(const bf16x8*)(Wj_b + row * ND + kk * 32 + q * 8);
      uiF[j][kk] = *(const bf16x8*)(Ui_b + row * ND + kk * 32 + q * 8);
    }
    mbF[j] = *(const f32x4*)(mb1 + (2 * wid + j) * 16 + q * 4);
    bpF[j] = *(const f32x4*)(bp  + (2 * wid + j) * 16 + q * 4);
  }

  const long stride = gridDim.x;
  long t = blockIdx.x;
  if (t >= NTILES) return;

  f32x4 xraw[8];
  auto loadx = [&](long tt) {
    const float* xp = X + (tt * 16 + r) * ND + q * 8;
#pragma unroll
    for (int kk = 0; kk < 4; ++kk) {
      xraw[2 * kk]     = *(const f32x4*)(xp + kk * 32);
      xraw[2 * kk + 1] = *(const f32x4*)(xp + kk * 32 + 4);
    }
  };
  loadx(t);
  int buf = 0;

  // store-phase coords: each thread owns (row, 16B chunk c)
  const int srow = tid >> 4, sc = tid & 15;
  const int srb = srow * 256 + ((sc * 16) ^ ((srow & 15) << 4));

  for (; t < NTILES; t += stride) {
    bf16x8 xf[4];
#pragma unroll
    for (int kk = 0; kk < 4; ++kk) {
      bf16x8 v;
#pragma unroll
      for (int i = 0; i < 4; ++i) {
        v[i]     = (bf16_t)xraw[2 * kk][i];
        v[i + 4] = (bf16_t)xraw[2 * kk + 1][i];
      }
      xf[kk] = v;
    }
    const long tn = t + stride;
    if (tn < NTILES) loadx(tn);   // prefetch next tile while MFMAs run

#pragma unroll
    for (int j = 0; j < 2; ++j) {
      f32x4 aS = {0.f, 0.f, 0.f, 0.f};
      f32x4 aZ = {0.f, 0.f, 0.f, 0.f};
      f32x4 aT = {0.f, 0.f, 0.f, 0.f};
#pragma unroll
      for (int kk = 0; kk < 4; ++kk) {
        aS = __builtin_amdgcn_mfma_f32_16x16x32_bf16(wiF[j][kk], xf[kk], aS, 0, 0, 0);
        aZ = __builtin_amdgcn_mfma_f32_16x16x32_bf16(wjF[j][kk], xf[kk], aZ, 0, 0, 0);
        aT = __builtin_amdgcn_mfma_f32_16x16x32_bf16(uiF[j][kk], xf[kk], aT, 0, 0, 0);
      }
      // lane holds ch = tile*16 + q*4 + i, edge = r; write LDS [edge][ch]
      const int tile = 2 * wid + j;
      const int wb = r * 256 + (((tile * 32) + q * 8) ^ ((r & 15) << 4));
      bf16x4 pS, pZ, pT;
#pragma unroll
      for (int i = 0; i < 4; ++i) {
        pS[i] = (bf16_t)(aS[i] + mbF[j][i]);
        pZ[i] = (bf16_t)aZ[i];
        pT[i] = (bf16_t)(aT[i] + bpF[j][i]);
      }
      *(bf16x4*)((char*)st[buf][0] + wb) = pS;
      *(bf16x4*)((char*)st[buf][1] + wb) = pZ;
      *(bf16x4*)((char*)st[buf][2] + wb) = pT;
    }
    __syncthreads();

    const long e = t * 16 + srow;
    const bf16x8 vS = *(const bf16x8*)((const char*)st[buf][0] + srb);
    const bf16x8 vZ = *(const bf16x8*)((const char*)st[buf][1] + srb);
    const bf16x8 vT = *(const bf16x8*)((const char*)st[buf][2] + srb);
    *(bf16x8*)(Sb + e * ND + sc * 8) = vS;
    *(bf16x8*)(Zb + e * ND + sc * 8) = vZ;
    *(bf16x8*)(T1 + e * 256 + sc * 8) = vT;   // T1 in out rows (stride 256 u16)
    buf ^= 1;
  }
}

// ---------------------------------------------------------------------------
// k2: hbar[e] = (1/16) * sum_k relu(S[e] + Z[adj[e][k]])
// Wave per edge; 64 lanes x 1 dword = full 256B row per gather instruction.
// (Round-3 version verbatim: 24 VGPR, max-occupancy free-running gathers.)
// ---------------------------------------------------------------------------
__global__ __launch_bounds__(256) void k2_gather(
    const u16* __restrict__ Zb, const u16* __restrict__ Sb,
    const int* __restrict__ adj, u16* __restrict__ Hb)
{
  const int tid = threadIdx.x, wid = tid >> 6, lane = tid & 63;
  const long e = (long)blockIdx.x * 4 + wid;
  if (e >= NE) return;
  const int d0 = lane * 2;

  const unsigned sbits = *(const unsigned*)(Sb + e * ND + d0);
  const float s0 = bf2f(sbits & 0xffffu);
  const float s1 = bf2f(sbits >> 16);

  float acc0 = 0.f, acc1 = 0.f;
  const int* ar = adj + e * NK;
#pragma unroll
  for (int k = 0; k < NK; ++k) {
    const int n = ar[k];
    const unsigned z = *(const unsigned*)(Zb + (long)n * ND + d0);
    acc0 += fmaxf(s0 + bf2f(z & 0xffffu), 0.f);
    acc1 += fmaxf(s1 + bf2f(z >> 16), 0.f);
  }
  const unsigned outw =
      (unsigned)f2bf(acc0 * 0.0625f) | ((unsigned)f2bf(acc1 * 0.0625f) << 16);
  *(unsigned*)(Hb + e * ND + d0) = outw;
}

// ---------------------------------------------------------------------------
// k3: u = relu(T1 + Hb@Wp^T); out = u@uW2^T + ub2.
// Wave w keeps Wp/W2 tiles {2w,2w+1} register-resident; grid-stride with
// prefetch. u exchanged via swizzled LDS (ubuf); out routed through a second
// swizzled f32 LDS tile (obuf) for fully-coalesced 512B-row stores.
// T1 aliases out rows: read (pre-barrier) before store (post-barrier).
// ---------------------------------------------------------------------------
__global__ __launch_bounds__(256) void k3_out(
    const u16* __restrict__ Hb, const u16* __restrict__ T1,
    const u16* __restrict__ Wp_b, const u16* __restrict__ W2_b,
    const float* __restrict__ ub2, float* __restrict__ out)
{
  __shared__ u16  ubuf[2][16 * ND];    // 2 x 4 KB
  __shared__ float obuf[2][16 * ND];   // 2 x 8 KB
  const int tid = threadIdx.x, wid = tid >> 6, lane = tid & 63;
  const int r = lane & 15, q = lane >> 4;

  bf16x8 wpF[2][4], w2F[2][4];
  f32x4 ubF[2];
#pragma unroll
  for (int j = 0; j < 2; ++j) {
    const int row = (2 * wid + j) * 16 + r;
#pragma unroll
    for (int kk = 0; kk < 4; ++kk) {
      wpF[j][kk] = *(const bf16x8*)(Wp_b + row * ND + kk * 32 + q * 8);
      w2F[j][kk] = *(const bf16x8*)(W2_b + row * ND + kk * 32 + q * 8);
    }
    ubF[j] = *(const f32x4*)(ub2 + (2 * wid + j) * 16 + q * 4);
  }

  const long stride = gridDim.x;
  long t = blockIdx.x;
  if (t >= NTILES) return;

  bf16x8 hraw[4];
  bf16x4 traw[2];
  auto loadin = [&](long tt) {
#pragma unroll
    for (int kk = 0; kk < 4; ++kk)
      hraw[kk] = *(const bf16x8*)(Hb + (tt * 16 + r) * ND + kk * 32 + q * 8);
#pragma unroll
    for (int j = 0; j < 2; ++j)
      traw[j] = *(const bf16x4*)(T1 + (tt * 16 + r) * 256 + (2 * wid + j) * 16 + q * 4);
  };
  loadin(t);
  int buf = 0;

  for (; t < NTILES; t += stride) {
    bf16x8 hf[4];
#pragma unroll
    for (int kk = 0; kk < 4; ++kk) hf[kk] = hraw[kk];
    f32x4 acc[2];
#pragma unroll
    for (int j = 0; j < 2; ++j)
#pragma unroll
      for (int i = 0; i < 4; ++i) acc[j][i] = (float)traw[j][i];

    const long tn = t + stride;
    if (tn < NTILES) loadin(tn);   // prefetch (same block owns tn: no alias race)

#pragma unroll
    for (int j = 0; j < 2; ++j)
#pragma unroll
      for (int kk = 0; kk < 4; ++kk)
        acc[j] = __builtin_amdgcn_mfma_f32_16x16x32_bf16(wpF[j][kk], hf[kk], acc[j], 0, 0, 0);

#pragma unroll
    for (int j = 0; j < 2; ++j) {
      bf16x4 u;
#pragma unroll
      for (int i = 0; i < 4; ++i) u[i] = (bf16_t)fmaxf(acc[j][i], 0.f);
      const int wb = r * 256 + ((((2 * wid + j) * 32) + q * 8) ^ ((r & 15) << 4));
      *(bf16x4*)((char*)ubuf[buf] + wb) = u;
    }
    __syncthreads();

    bf16x8 uf[4];
#pragma unroll
    for (int kk = 0; kk < 4; ++kk) {
      const int rb = r * 256 + ((kk * 64 + q * 16) ^ ((r & 15) << 4));
      uf[kk] = *(const bf16x8*)((const char*)ubuf[buf] + rb);
    }

#pragma unroll
    for (int j = 0; j < 2; ++j) {
      f32x4 o = {0.f, 0.f, 0.f, 0.f};
#pragma unroll
      for (int kk = 0; kk < 4; ++kk)
        o = __builtin_amdgcn_mfma_f32_16x16x32_bf16(w2F[j][kk], uf[kk], o, 0, 0, 0);
#pragma unroll
      for (int i = 0; i < 4; ++i) o[i] += ubF[j][i];
      // lane: ch' = tile*16+q*4.., edge r -> obuf[edge][ch'] (f32, swizzled)
      const int wb = r * 512 + ((((2 * wid + j) * 64) + q * 16) ^ ((r & 15) << 4));
      *(f32x4*)((char*)obuf[buf] + wb) = o;
    }
    __syncthreads();

    // coalesced out store: 2 rounds x 256 threads x 16B = 16 rows x 512 B
#pragma unroll
    for (int rd = 0; rd < 2; ++rd) {
      const int idx = tid + rd * 256;
      const int row = idx >> 5, c = idx & 31;
      const int rb = row * 512 + ((c * 16) ^ ((row & 15) << 4));
      const f32x4 v = *(const f32x4*)((const char*)obuf[buf] + rb);
      *(f32x4*)(out + (t * 16 + row) * ND + c * 4) = v;
    }
    buf ^= 1;
  }
}

extern "C" void kernel_launch(void* const* d_in, const int* in_sizes, int n_in,
                              void* d_out, int out_size, void* d_ws, size_t ws_size,
                              hipStream_t stream)
{
  (void)in_sizes; (void)n_in; (void)out_size; (void)ws_size;
  const float* X   = (const float*)d_in[0];
  const int*   adj = (const int*)d_in[1];
  const float* mW1 = (const float*)d_in[2];
  const float* mb1 = (const float*)d_in[3];
  const float* mW2 = (const float*)d_in[4];
  const float* mb2 = (const float*)d_in[5];
  const float* uW1 = (const float*)d_in[6];
  const float* ub1 = (const float*)d_in[7];
  const float* uW2 = (const float*)d_in[8];
  const float* ub2 = (const float*)d_in[9];
  float* out = (float*)d_out;

  u16* ws16 = (u16*)d_ws;
  u16* Sb   = ws16;                              // E*D bf16
  u16* Zb   = Sb + (size_t)NE * ND;              // E*D bf16
  u16* Hb   = Zb + (size_t)NE * ND;              // E*D bf16
  u16* Wi_b = Hb + (size_t)NE * ND;              // 128*128 bf16 each:
  u16* Wj_b = Wi_b + 128 * 128;
  u16* Ui_b = Wj_b + 128 * 128;
  u16* Wp_b = Ui_b + 128 * 128;
  u16* W2_b = Wp_b + 128 * 128;
  float* bp = (float*)(W2_b + 128 * 128);        // 128 f32
  u16* T1   = (u16*)d_out;                       // bf16 T1, stride 256, in out rows

  k_prep<<<128, 128, 0, stream>>>(mW1, uW1, uW2, mW2, ub1, mb2,
                                  Wi_b, Wj_b, Ui_b, Wp_b, W2_b, bp);

  k1_szt<<<2048, 256, 0, stream>>>(X, Wi_b, Wj_b, Ui_b, mb1, bp, Sb, Zb, T1);

  const int nblk_gather = (NE + 3) / 4;     // 25000
  k2_gather<<<nblk_gather, 256, 0, stream>>>(Zb, Sb, adj, Hb);

  k3_out<<<2048, 256, 0, stream>>>(Hb, T1, Wp_b, W2_b, ub2, out);
}

// Round 6
// 130.196 us; speedup vs baseline: 1.2560x; 1.2116x over previous
//
#include <hip/hip_runtime.h>
#include <hip/hip_bf16.h>

#define NE 100000
#define NK 16
#define ND 128
#define NTILES 6250   // NE / 16

typedef __bf16 bf16_t;
typedef bf16_t bf16x8 __attribute__((ext_vector_type(8)));
typedef bf16_t bf16x4 __attribute__((ext_vector_type(4)));
typedef float f32x4 __attribute__((ext_vector_type(4)));
typedef unsigned short u16;

__device__ __forceinline__ u16 f2bf(float f) {
  bf16_t h = (bf16_t)f;
  return __builtin_bit_cast(u16, h);
}
__device__ __forceinline__ float bf2f(unsigned int bits) {
  return __builtin_bit_cast(float, bits << 16);
}

// ---------------------------------------------------------------------------
// k_prep: bf16-convert weights; fold Wp = Um@mW2, bp = ub1 + Um@mb2.
// ---------------------------------------------------------------------------
__global__ void k_prep(const float* __restrict__ mW1, const float* __restrict__ uW1,
                       const float* __restrict__ uW2, const float* __restrict__ mW2,
                       const float* __restrict__ ub1, const float* __restrict__ mb2,
                       u16* __restrict__ Wi_b, u16* __restrict__ Wj_b,
                       u16* __restrict__ Ui_b, u16* __restrict__ Wp_b,
                       u16* __restrict__ W2_b, float* __restrict__ bp)
{
  const int o = blockIdx.x, t = threadIdx.x;
  Wi_b[o * ND + t] = f2bf(mW1[o * 256 + t]);
  Wj_b[o * ND + t] = f2bf(mW1[o * 256 + 128 + t]);
  Ui_b[o * ND + t] = f2bf(uW1[o * 256 + t]);
  W2_b[o * ND + t] = f2bf(uW2[o * ND + t]);
  float acc = 0.f;
  for (int p = 0; p < 128; ++p)
    acc += uW1[o * 256 + 128 + p] * mW2[p * 128 + t];
  Wp_b[o * ND + t] = f2bf(acc);
  if (t == 0) {
    float b = ub1[o];
    for (int p = 0; p < 128; ++p) b += uW1[o * 256 + 128 + p] * mb2[p];
    bp[o] = b;
  }
}

// ---------------------------------------------------------------------------
// k1: S = X@Wi^T + mb1, Z = X@Wj^T, T1 = X@Ui^T + bp (all bf16; T1 in out
// rows at u16-stride 256). 512 threads / 8 waves; wave w owns col-tile w of
// Wi/Wj/Ui (48 VGPR of weights). X tile (8 KB f32) is staged ONCE per block:
// coalesced f32x4/thread -> cvt -> swizzled bf16 LDS tile; frags via
// ds_read_b128. Eliminates the 4x-redundant per-wave X loads of r3-r5.
// ---------------------------------------------------------------------------
__global__ __launch_bounds__(512) void k1_szt(
    const float* __restrict__ X, const u16* __restrict__ Wi_b,
    const u16* __restrict__ Wj_b, const u16* __restrict__ Ui_b,
    const float* __restrict__ mb1, const float* __restrict__ bp,
    u16* __restrict__ Sb, u16* __restrict__ Zb, u16* __restrict__ T1)
{
  __shared__ u16 xt[16 * ND];   // 4 KB bf16 X tile, 16B-chunk XOR swizzle
  const int tid = threadIdx.x, wid = tid >> 6, lane = tid & 63;
  const int r = lane & 15, q = lane >> 4;

  // wave wid owns output-channel tile wid of each matrix
  bf16x8 wiF[4], wjF[4], uiF[4];
  f32x4 mbF, bpF;
  {
    const int row = wid * 16 + r;
#pragma unroll
    for (int kk = 0; kk < 4; ++kk) {
      wiF[kk] = *(const bf16x8*)(Wi_b + row * ND + kk * 32 + q * 8);
      wjF[kk] = *(const bf16x8*)(Wj_b + row * ND + kk * 32 + q * 8);
      uiF[kk] = *(const bf16x8*)(Ui_b + row * ND + kk * 32 + q * 8);
    }
    mbF = *(const f32x4*)(mb1 + wid * 16 + q * 4);
    bpF = *(const f32x4*)(bp  + wid * 16 + q * 4);
  }

  // staging coords: thread -> (row rs, f32x4 chunk cs); 512 x 16B = 8 KB tile
  const int rs = tid >> 5, cs = tid & 31;
  // bf16 dest: 8B at row rs, byte cs*8; chunk=(cs>>1), swizzle chunk^(rs&15)
  const int stb = rs * 256 + ((((cs >> 1) ^ (rs & 15)) << 4) | ((cs & 1) << 3));

  const long stride = gridDim.x;
  long t = blockIdx.x;
  if (t >= NTILES) return;

  f32x4 xr;
  auto gload = [&](long tt) {
    xr = *(const f32x4*)(X + (tt * 16 + rs) * ND + cs * 4);
  };
  auto stage = [&]() {
    bf16x4 b;
#pragma unroll
    for (int i = 0; i < 4; ++i) b[i] = (bf16_t)xr[i];
    *(bf16x4*)((char*)xt + stb) = b;
  };

  gload(t);
  stage();
  __syncthreads();

  for (; t < NTILES; t += stride) {
    const long tn = t + stride;
    if (tn < NTILES) gload(tn);   // prefetch next tile into regs

    bf16x8 xf[4];
#pragma unroll
    for (int kk = 0; kk < 4; ++kk)
      xf[kk] = *(const bf16x8*)((const char*)xt +
               r * 256 + (((kk * 4 + q) ^ (r & 15)) << 4));

    f32x4 aS = {0.f, 0.f, 0.f, 0.f};
    f32x4 aZ = {0.f, 0.f, 0.f, 0.f};
    f32x4 aT = {0.f, 0.f, 0.f, 0.f};
#pragma unroll
    for (int kk = 0; kk < 4; ++kk) {
      aS = __builtin_amdgcn_mfma_f32_16x16x32_bf16(wiF[kk], xf[kk], aS, 0, 0, 0);
      aZ = __builtin_amdgcn_mfma_f32_16x16x32_bf16(wjF[kk], xf[kk], aZ, 0, 0, 0);
      aT = __builtin_amdgcn_mfma_f32_16x16x32_bf16(uiF[kk], xf[kk], aT, 0, 0, 0);
    }

    // lane holds ch = wid*16 + q*4 + i, edge = r
    const long rowS = (t * 16 + r) * ND;
    const long rowT = (t * 16 + r) * 256;
    const int cb = wid * 16 + q * 4;
    bf16x4 pS, pZ, pT;
#pragma unroll
    for (int i = 0; i < 4; ++i) {
      pS[i] = (bf16_t)(aS[i] + mbF[i]);
      pZ[i] = (bf16_t)aZ[i];
      pT[i] = (bf16_t)(aT[i] + bpF[i]);
    }
    *(bf16x4*)(Sb + rowS + cb) = pS;
    *(bf16x4*)(Zb + rowS + cb) = pZ;
    *(bf16x4*)(T1 + rowT + cb) = pT;

    __syncthreads();              // (A) all frag reads of xt done
    if (tn < NTILES) stage();     // write next tile
    __syncthreads();              // (B) staged tile visible
  }
}

// ---------------------------------------------------------------------------
// k2: hbar[e] = (1/16) * sum_k relu(S[e] + Z[adj[e][k]])
// Wave per edge; 64 lanes x 1 dword = full 256B row per gather instruction.
// (Round-3 version verbatim — unchanged control.)
// ---------------------------------------------------------------------------
__global__ __launch_bounds__(256) void k2_gather(
    const u16* __restrict__ Zb, const u16* __restrict__ Sb,
    const int* __restrict__ adj, u16* __restrict__ Hb)
{
  const int tid = threadIdx.x, wid = tid >> 6, lane = tid & 63;
  const long e = (long)blockIdx.x * 4 + wid;
  if (e >= NE) return;
  const int d0 = lane * 2;

  const unsigned sbits = *(const unsigned*)(Sb + e * ND + d0);
  const float s0 = bf2f(sbits & 0xffffu);
  const float s1 = bf2f(sbits >> 16);

  float acc0 = 0.f, acc1 = 0.f;
  const int* ar = adj + e * NK;
#pragma unroll
  for (int k = 0; k < NK; ++k) {
    const int n = ar[k];
    const unsigned z = *(const unsigned*)(Zb + (long)n * ND + d0);
    acc0 += fmaxf(s0 + bf2f(z & 0xffffu), 0.f);
    acc1 += fmaxf(s1 + bf2f(z >> 16), 0.f);
  }
  const unsigned outw =
      (unsigned)f2bf(acc0 * 0.0625f) | ((unsigned)f2bf(acc1 * 0.0625f) << 16);
  *(unsigned*)(Hb + e * ND + d0) = outw;
}

// ---------------------------------------------------------------------------
// k3: u = relu(T1 + Hb@Wp^T); out = u@uW2^T + ub2. 512 threads / 8 waves;
// wave w owns col-tile w of Wp and W2. Hb tile staged once per block into
// swizzled LDS (same dedup as k1); u exchanged via second swizzled LDS tile.
// T1 aliases out rows (read pre-store, block owns the tile exclusively).
// ---------------------------------------------------------------------------
__global__ __launch_bounds__(512) void k3_out(
    const u16* __restrict__ Hb, const u16* __restrict__ T1,
    const u16* __restrict__ Wp_b, const u16* __restrict__ W2_b,
    const float* __restrict__ ub2, float* __restrict__ out)
{
  __shared__ u16 ht[16 * ND];   // 4 KB staged hbar tile
  __shared__ u16 ut[16 * ND];   // 4 KB u exchange
  const int tid = threadIdx.x, wid = tid >> 6, lane = tid & 63;
  const int r = lane & 15, q = lane >> 4;

  bf16x8 wpF[4], w2F[4];
  f32x4 ubF;
  {
    const int row = wid * 16 + r;
#pragma unroll
    for (int kk = 0; kk < 4; ++kk) {
      wpF[kk] = *(const bf16x8*)(Wp_b + row * ND + kk * 32 + q * 8);
      w2F[kk] = *(const bf16x8*)(W2_b + row * ND + kk * 32 + q * 8);
    }
    ubF = *(const f32x4*)(ub2 + wid * 16 + q * 4);
  }

  const int rs = tid >> 5, cs = tid & 31;   // 8B per thread: 512 x 8B = 4 KB
  const int stb = rs * 256 + ((((cs >> 1) ^ (rs & 15)) << 4) | ((cs & 1) << 3));

  const long stride = gridDim.x;
  long t = blockIdx.x;
  if (t >= NTILES) return;

  bf16x4 hr;
  auto gload = [&](long tt) {
    hr = *(const bf16x4*)(Hb + (tt * 16 + rs) * ND + cs * 4);
  };
  gload(t);
  *(bf16x4*)((char*)ht + stb) = hr;
  __syncthreads();

  for (; t < NTILES; t += stride) {
    const long tn = t + stride;
    if (tn < NTILES) gload(tn);   // prefetch next hbar tile into regs

    bf16x8 hf[4];
#pragma unroll
    for (int kk = 0; kk < 4; ++kk)
      hf[kk] = *(const bf16x8*)((const char*)ht +
               r * 256 + (((kk * 4 + q) ^ (r & 15)) << 4));

    f32x4 acc;
    {
      const bf16x4 tv = *(const bf16x4*)(T1 + (t * 16 + r) * 256 + wid * 16 + q * 4);
#pragma unroll
      for (int i = 0; i < 4; ++i) acc[i] = (float)tv[i];
    }
#pragma unroll
    for (int kk = 0; kk < 4; ++kk)
      acc = __builtin_amdgcn_mfma_f32_16x16x32_bf16(wpF[kk], hf[kk], acc, 0, 0, 0);

    bf16x4 u;
#pragma unroll
    for (int i = 0; i < 4; ++i) u[i] = (bf16_t)fmaxf(acc[i], 0.f);
    // lane: edge r, ch = wid*16+q*4 -> byte wid*32+q*8, chunk wid*2+(q>>1)
    const int uwb = r * 256 + ((((wid * 2 + (q >> 1)) ^ (r & 15)) << 4) | ((q & 1) << 3));

    __syncthreads();              // (A) prev ut reads + this-iter ht reads done
    *(bf16x4*)((char*)ut + uwb) = u;
    if (tn < NTILES) *(bf16x4*)((char*)ht + stb) = hr;
    __syncthreads();              // (B) ut + next ht visible

    bf16x8 uf[4];
#pragma unroll
    for (int kk = 0; kk < 4; ++kk)
      uf[kk] = *(const bf16x8*)((const char*)ut +
               r * 256 + (((kk * 4 + q) ^ (r & 15)) << 4));

    f32x4 o = {0.f, 0.f, 0.f, 0.f};
#pragma unroll
    for (int kk = 0; kk < 4; ++kk)
      o = __builtin_amdgcn_mfma_f32_16x16x32_bf16(w2F[kk], uf[kk], o, 0, 0, 0);
#pragma unroll
    for (int i = 0; i < 4; ++i) o[i] += ubF[i];
    *(f32x4*)(out + (t * 16 + r) * ND + wid * 16 + q * 4) = o;
  }
}

extern "C" void kernel_launch(void* const* d_in, const int* in_sizes, int n_in,
                              void* d_out, int out_size, void* d_ws, size_t ws_size,
                              hipStream_t stream)
{
  (void)in_sizes; (void)n_in; (void)out_size; (void)ws_size;
  const float* X   = (const float*)d_in[0];
  const int*   adj = (const int*)d_in[1];
  const float* mW1 = (const float*)d_in[2];
  const float* mb1 = (const float*)d_in[3];
  const float* mW2 = (const float*)d_in[4];
  const float* mb2 = (const float*)d_in[5];
  const float* uW1 = (const float*)d_in[6];
  const float* ub1 = (const float*)d_in[7];
  const float* uW2 = (const float*)d_in[8];
  const float* ub2 = (const float*)d_in[9];
  float* out = (float*)d_out;

  u16* ws16 = (u16*)d_ws;
  u16* Sb   = ws16;                              // E*D bf16
  u16* Zb   = Sb + (size_t)NE * ND;              // E*D bf16
  u16* Hb   = Zb + (size_t)NE * ND;              // E*D bf16
  u16* Wi_b = Hb + (size_t)NE * ND;              // 128*128 bf16 each:
  u16* Wj_b = Wi_b + 128 * 128;
  u16* Ui_b = Wj_b + 128 * 128;
  u16* Wp_b = Ui_b + 128 * 128;
  u16* W2_b = Wp_b + 128 * 128;
  float* bp = (float*)(W2_b + 128 * 128);        // 128 f32
  u16* T1   = (u16*)d_out;                       // bf16 T1, stride 256, in out rows

  k_prep<<<128, 128, 0, stream>>>(mW1, uW1, uW2, mW2, ub1, mb2,
                                  Wi_b, Wj_b, Ui_b, Wp_b, W2_b, bp);

  k1_szt<<<1024, 512, 0, stream>>>(X, Wi_b, Wj_b, Ui_b, mb1, bp, Sb, Zb, T1);

  const int nblk_gather = (NE + 3) / 4;     // 25000
  k2_gather<<<nblk_gather, 256, 0, stream>>>(Zb, Sb, adj, Hb);

  k3_out<<<1024, 512, 0, stream>>>(Hb, T1, Wp_b, W2_b, ub2, out);
}

// Round 7
// 104.375 us; speedup vs baseline: 1.5668x; 1.2474x over previous
//
#include <hip/hip_runtime.h>
#include <hip/hip_bf16.h>

#define NE 100000
#define NK 16
#define ND 128
#define NTILES 6250   // NE / 16

typedef __bf16 bf16_t;
typedef bf16_t bf16x8 __attribute__((ext_vector_type(8)));
typedef bf16_t bf16x4 __attribute__((ext_vector_type(4)));
typedef float f32x4 __attribute__((ext_vector_type(4)));
typedef float f32x2 __attribute__((ext_vector_type(2)));
typedef unsigned short u16;
typedef unsigned char u8;

__device__ __forceinline__ u16 f2bf(float f) {
  bf16_t h = (bf16_t)f;
  return __builtin_bit_cast(u16, h);
}

// ---------------------------------------------------------------------------
// k_prep: bf16-convert weights; fold Wp = Um@mW2, bp = ub1 + Um@mb2.
// ---------------------------------------------------------------------------
__global__ void k_prep(const float* __restrict__ mW1, const float* __restrict__ uW1,
                       const float* __restrict__ uW2, const float* __restrict__ mW2,
                       const float* __restrict__ ub1, const float* __restrict__ mb2,
                       u16* __restrict__ Wi_b, u16* __restrict__ Wj_b,
                       u16* __restrict__ Ui_b, u16* __restrict__ Wp_b,
                       u16* __restrict__ W2_b, float* __restrict__ bp)
{
  const int o = blockIdx.x, t = threadIdx.x;
  Wi_b[o * ND + t] = f2bf(mW1[o * 256 + t]);
  Wj_b[o * ND + t] = f2bf(mW1[o * 256 + 128 + t]);
  Ui_b[o * ND + t] = f2bf(uW1[o * 256 + t]);
  W2_b[o * ND + t] = f2bf(uW2[o * ND + t]);
  float acc = 0.f;
  for (int p = 0; p < 128; ++p)
    acc += uW1[o * 256 + 128 + p] * mW2[p * 128 + t];
  Wp_b[o * ND + t] = f2bf(acc);
  if (t == 0) {
    float b = ub1[o];
    for (int p = 0; p < 128; ++p) b += uW1[o * 256 + 128 + p] * mb2[p];
    bp[o] = b;
  }
}

// ---------------------------------------------------------------------------
// k1: S = X@Wi^T + mb1 (bf16), Z = X@Wj^T (fp8 e4m3 -> halves k2's gather
// bytes), T1 = X@Ui^T + bp (bf16 in out rows, u16-stride 256).
// 512 threads / 8 waves; wave w owns col-tile w of Wi/Wj/Ui. X tile staged
// once per block via swizzled LDS (dedup), frags via ds_read_b128.
// ---------------------------------------------------------------------------
__global__ __launch_bounds__(512) void k1_szt(
    const float* __restrict__ X, const u16* __restrict__ Wi_b,
    const u16* __restrict__ Wj_b, const u16* __restrict__ Ui_b,
    const float* __restrict__ mb1, const float* __restrict__ bp,
    u16* __restrict__ Sb, u8* __restrict__ Zf8, u16* __restrict__ T1)
{
  __shared__ u16 xt[16 * ND];   // 4 KB bf16 X tile, 16B-chunk XOR swizzle
  const int tid = threadIdx.x, wid = tid >> 6, lane = tid & 63;
  const int r = lane & 15, q = lane >> 4;

  bf16x8 wiF[4], wjF[4], uiF[4];
  f32x4 mbF, bpF;
  {
    const int row = wid * 16 + r;
#pragma unroll
    for (int kk = 0; kk < 4; ++kk) {
      wiF[kk] = *(const bf16x8*)(Wi_b + row * ND + kk * 32 + q * 8);
      wjF[kk] = *(const bf16x8*)(Wj_b + row * ND + kk * 32 + q * 8);
      uiF[kk] = *(const bf16x8*)(Ui_b + row * ND + kk * 32 + q * 8);
    }
    mbF = *(const f32x4*)(mb1 + wid * 16 + q * 4);
    bpF = *(const f32x4*)(bp  + wid * 16 + q * 4);
  }

  const int rs = tid >> 5, cs = tid & 31;
  const int stb = rs * 256 + ((((cs >> 1) ^ (rs & 15)) << 4) | ((cs & 1) << 3));

  const long stride = gridDim.x;
  long t = blockIdx.x;
  if (t >= NTILES) return;

  f32x4 xr;
  auto gload = [&](long tt) {
    xr = *(const f32x4*)(X + (tt * 16 + rs) * ND + cs * 4);
  };
  auto stage = [&]() {
    bf16x4 b;
#pragma unroll
    for (int i = 0; i < 4; ++i) b[i] = (bf16_t)xr[i];
    *(bf16x4*)((char*)xt + stb) = b;
  };

  gload(t);
  stage();
  __syncthreads();

  for (; t < NTILES; t += stride) {
    const long tn = t + stride;
    if (tn < NTILES) gload(tn);

    bf16x8 xf[4];
#pragma unroll
    for (int kk = 0; kk < 4; ++kk)
      xf[kk] = *(const bf16x8*)((const char*)xt +
               r * 256 + (((kk * 4 + q) ^ (r & 15)) << 4));

    f32x4 aS = {0.f, 0.f, 0.f, 0.f};
    f32x4 aZ = {0.f, 0.f, 0.f, 0.f};
    f32x4 aT = {0.f, 0.f, 0.f, 0.f};
#pragma unroll
    for (int kk = 0; kk < 4; ++kk) {
      aS = __builtin_amdgcn_mfma_f32_16x16x32_bf16(wiF[kk], xf[kk], aS, 0, 0, 0);
      aZ = __builtin_amdgcn_mfma_f32_16x16x32_bf16(wjF[kk], xf[kk], aZ, 0, 0, 0);
      aT = __builtin_amdgcn_mfma_f32_16x16x32_bf16(uiF[kk], xf[kk], aT, 0, 0, 0);
    }

    const long rowS = (t * 16 + r) * ND;
    const long rowT = (t * 16 + r) * 256;
    const int cb = wid * 16 + q * 4;
    bf16x4 pS, pT;
#pragma unroll
    for (int i = 0; i < 4; ++i) {
      pS[i] = (bf16_t)(aS[i] + mbF[i]);
      pT[i] = (bf16_t)(aT[i] + bpF[i]);
    }
    unsigned zpk = 0;
    zpk = __builtin_amdgcn_cvt_pk_fp8_f32(aZ[0], aZ[1], zpk, false);
    zpk = __builtin_amdgcn_cvt_pk_fp8_f32(aZ[2], aZ[3], zpk, true);
    *(bf16x4*)(Sb + rowS + cb) = pS;
    *(unsigned*)(Zf8 + rowS + cb) = zpk;   // fp8 row stride = ND bytes
    *(bf16x4*)(T1 + rowT + cb) = pT;

    __syncthreads();
    if (tn < NTILES) stage();
    __syncthreads();
  }
}

// ---------------------------------------------------------------------------
// k2: hbar[e] = (1/16) * sum_k relu(S[e] + Z[adj[e][k]]), Z in fp8 e4m3.
// Wave = 2 edges: half-wave per edge, lane covers 4 channels (1 dword fp8).
// Adjacency preloaded into lanes once, redistributed via __shfl (LDS pipe).
// Gather row = 128B contiguous per half-wave.
// ---------------------------------------------------------------------------
__global__ __launch_bounds__(256) void k2_gather(
    const u8* __restrict__ Zf8, const u16* __restrict__ Sb,
    const int* __restrict__ adj, u16* __restrict__ Hb)
{
  const int tid = threadIdx.x, w4 = tid >> 6, lane = tid & 63;
  const int sub = lane >> 5, l = lane & 31;
  const long e = (long)blockIdx.x * 8 + w4 * 2 + sub;
  const int c0 = l * 4;

  const bf16x4 sv = *(const bf16x4*)(Sb + e * ND + c0);
  f32x4 s;
#pragma unroll
  for (int i = 0; i < 4; ++i) s[i] = (float)sv[i];

  // lane (lane&15) of each half-wave holds adjacency index (lane&15)
  const int myidx = adj[e * NK + (lane & 15)];

  f32x4 acc = {0.f, 0.f, 0.f, 0.f};
#pragma unroll
  for (int k = 0; k < NK; ++k) {
    const int n = __shfl(myidx, (lane & 32) + k);
    const unsigned zw = *(const unsigned*)(Zf8 + (long)n * ND + c0);
    const f32x2 zlo = __builtin_amdgcn_cvt_pk_f32_fp8(zw, false);
    const f32x2 zhi = __builtin_amdgcn_cvt_pk_f32_fp8(zw, true);
    f32x4 z;
    z[0] = zlo[0]; z[1] = zlo[1]; z[2] = zhi[0]; z[3] = zhi[1];
    f32x4 v = s + z;                       // v_pk_add_f32
#pragma unroll
    for (int i = 0; i < 4; ++i) v[i] = fmaxf(v[i], 0.f);
    acc += v;                              // v_pk_add_f32
  }

  bf16x4 hv;
#pragma unroll
  for (int i = 0; i < 4; ++i) hv[i] = (bf16_t)(acc[i] * 0.0625f);
  *(bf16x4*)(Hb + e * ND + c0) = hv;
}

// ---------------------------------------------------------------------------
// k3: u = relu(T1 + Hb@Wp^T); out = u@uW2^T + ub2. 512 threads / 8 waves;
// wave w owns col-tile w of Wp/W2; Hb tile staged once per block (dedup);
// u exchanged via swizzled LDS. T1 aliases out rows.
// ---------------------------------------------------------------------------
__global__ __launch_bounds__(512) void k3_out(
    const u16* __restrict__ Hb, const u16* __restrict__ T1,
    const u16* __restrict__ Wp_b, const u16* __restrict__ W2_b,
    const float* __restrict__ ub2, float* __restrict__ out)
{
  __shared__ u16 ht[16 * ND];
  __shared__ u16 ut[16 * ND];
  const int tid = threadIdx.x, wid = tid >> 6, lane = tid & 63;
  const int r = lane & 15, q = lane >> 4;

  bf16x8 wpF[4], w2F[4];
  f32x4 ubF;
  {
    const int row = wid * 16 + r;
#pragma unroll
    for (int kk = 0; kk < 4; ++kk) {
      wpF[kk] = *(const bf16x8*)(Wp_b + row * ND + kk * 32 + q * 8);
      w2F[kk] = *(const bf16x8*)(W2_b + row * ND + kk * 32 + q * 8);
    }
    ubF = *(const f32x4*)(ub2 + wid * 16 + q * 4);
  }

  const int rs = tid >> 5, cs = tid & 31;
  const int stb = rs * 256 + ((((cs >> 1) ^ (rs & 15)) << 4) | ((cs & 1) << 3));

  const long stride = gridDim.x;
  long t = blockIdx.x;
  if (t >= NTILES) return;

  bf16x4 hr;
  auto gload = [&](long tt) {
    hr = *(const bf16x4*)(Hb + (tt * 16 + rs) * ND + cs * 4);
  };
  gload(t);
  *(bf16x4*)((char*)ht + stb) = hr;
  __syncthreads();

  for (; t < NTILES; t += stride) {
    const long tn = t + stride;
    if (tn < NTILES) gload(tn);

    bf16x8 hf[4];
#pragma unroll
    for (int kk = 0; kk < 4; ++kk)
      hf[kk] = *(const bf16x8*)((const char*)ht +
               r * 256 + (((kk * 4 + q) ^ (r & 15)) << 4));

    f32x4 acc;
    {
      const bf16x4 tv = *(const bf16x4*)(T1 + (t * 16 + r) * 256 + wid * 16 + q * 4);
#pragma unroll
      for (int i = 0; i < 4; ++i) acc[i] = (float)tv[i];
    }
#pragma unroll
    for (int kk = 0; kk < 4; ++kk)
      acc = __builtin_amdgcn_mfma_f32_16x16x32_bf16(wpF[kk], hf[kk], acc, 0, 0, 0);

    bf16x4 u;
#pragma unroll
    for (int i = 0; i < 4; ++i) u[i] = (bf16_t)fmaxf(acc[i], 0.f);
    const int uwb = r * 256 + ((((wid * 2 + (q >> 1)) ^ (r & 15)) << 4) | ((q & 1) << 3));

    __syncthreads();
    *(bf16x4*)((char*)ut + uwb) = u;
    if (tn < NTILES) *(bf16x4*)((char*)ht + stb) = hr;
    __syncthreads();

    bf16x8 uf[4];
#pragma unroll
    for (int kk = 0; kk < 4; ++kk)
      uf[kk] = *(const bf16x8*)((const char*)ut +
               r * 256 + (((kk * 4 + q) ^ (r & 15)) << 4));

    f32x4 o = {0.f, 0.f, 0.f, 0.f};
#pragma unroll
    for (int kk = 0; kk < 4; ++kk)
      o = __builtin_amdgcn_mfma_f32_16x16x32_bf16(w2F[kk], uf[kk], o, 0, 0, 0);
#pragma unroll
    for (int i = 0; i < 4; ++i) o[i] += ubF[i];
    *(f32x4*)(out + (t * 16 + r) * ND + wid * 16 + q * 4) = o;
  }
}

extern "C" void kernel_launch(void* const* d_in, const int* in_sizes, int n_in,
                              void* d_out, int out_size, void* d_ws, size_t ws_size,
                              hipStream_t stream)
{
  (void)in_sizes; (void)n_in; (void)out_size; (void)ws_size;
  const float* X   = (const float*)d_in[0];
  const int*   adj = (const int*)d_in[1];
  const float* mW1 = (const float*)d_in[2];
  const float* mb1 = (const float*)d_in[3];
  const float* mW2 = (const float*)d_in[4];
  const float* mb2 = (const float*)d_in[5];
  const float* uW1 = (const float*)d_in[6];
  const float* ub1 = (const float*)d_in[7];
  const float* uW2 = (const float*)d_in[8];
  const float* ub2 = (const float*)d_in[9];
  float* out = (float*)d_out;

  u16* ws16 = (u16*)d_ws;
  u16* Sb   = ws16;                              // E*D bf16 (25.6 MB)
  u16* Hb   = Sb + (size_t)NE * ND;              // E*D bf16 (25.6 MB)
  u8*  Zf8  = (u8*)(Hb + (size_t)NE * ND);       // E*D fp8  (12.8 MB)
  u16* Wi_b = (u16*)(Zf8 + (size_t)NE * ND);     // 128*128 bf16 each:
  u16* Wj_b = Wi_b + 128 * 128;
  u16* Ui_b = Wj_b + 128 * 128;
  u16* Wp_b = Ui_b + 128 * 128;
  u16* W2_b = Wp_b + 128 * 128;
  float* bp = (float*)(W2_b + 128 * 128);        // 128 f32
  u16* T1   = (u16*)d_out;                       // bf16 T1, stride 256, in out rows

  k_prep<<<128, 128, 0, stream>>>(mW1, uW1, uW2, mW2, ub1, mb2,
                                  Wi_b, Wj_b, Ui_b, Wp_b, W2_b, bp);

  k1_szt<<<1024, 512, 0, stream>>>(X, Wi_b, Wj_b, Ui_b, mb1, bp, Sb, Zf8, T1);

  k2_gather<<<NE / 8, 256, 0, stream>>>(Zf8, Sb, adj, Hb);

  k3_out<<<1024, 512, 0, stream>>>(Hb, T1, Wp_b, W2_b, ub2, out);
}

// Round 8
// 97.462 us; speedup vs baseline: 1.6779x; 1.0709x over previous
//
#include <hip/hip_runtime.h>
#include <hip/hip_bf16.h>

#define NE 100000
#define NK 16
#define ND 128
#define NTILES 6250   // NE / 16

typedef __bf16 bf16_t;
typedef bf16_t bf16x8 __attribute__((ext_vector_type(8)));
typedef bf16_t bf16x4 __attribute__((ext_vector_type(4)));
typedef float f32x4 __attribute__((ext_vector_type(4)));
typedef float f32x2 __attribute__((ext_vector_type(2)));
typedef unsigned short u16;
typedef unsigned char u8;

__device__ __forceinline__ u16 f2bf(float f) {
  bf16_t h = (bf16_t)f;
  return __builtin_bit_cast(u16, h);
}

// ---------------------------------------------------------------------------
// k_prep: bf16-convert weights; fold Wp = Um@mW2, bp = ub1 + Um@mb2.
// ---------------------------------------------------------------------------
__global__ void k_prep(const float* __restrict__ mW1, const float* __restrict__ uW1,
                       const float* __restrict__ uW2, const float* __restrict__ mW2,
                       const float* __restrict__ ub1, const float* __restrict__ mb2,
                       u16* __restrict__ Wi_b, u16* __restrict__ Wj_b,
                       u16* __restrict__ Ui_b, u16* __restrict__ Wp_b,
                       u16* __restrict__ W2_b, float* __restrict__ bp)
{
  const int o = blockIdx.x, t = threadIdx.x;
  Wi_b[o * ND + t] = f2bf(mW1[o * 256 + t]);
  Wj_b[o * ND + t] = f2bf(mW1[o * 256 + 128 + t]);
  Ui_b[o * ND + t] = f2bf(uW1[o * 256 + t]);
  W2_b[o * ND + t] = f2bf(uW2[o * ND + t]);
  float acc = 0.f;
  for (int p = 0; p < 128; ++p)
    acc += uW1[o * 256 + 128 + p] * mW2[p * 128 + t];
  Wp_b[o * ND + t] = f2bf(acc);
  if (t == 0) {
    float b = ub1[o];
    for (int p = 0; p < 128; ++p) b += uW1[o * 256 + 128 + p] * mb2[p];
    bp[o] = b;
  }
}

// ---------------------------------------------------------------------------
// k1: S = X@Wi^T + mb1 (bf16), Z = X@Wj^T (fp8 e4m3), T1 = X@Ui^T + bp
// (bf16 in out rows, u16-stride 256). 512 threads / 8 waves; wave w owns
// col-tile w of Wi/Wj/Ui. X tile staged once per block (dedup). NEW r8:
// coalesced LDS-transpose epilogue — accs go to swizzled LDS tiles, then
// each thread stores one contiguous chunk (full-line writes; kills the
// 32B-partial-line RFO traffic that capped r7's k1 at 2 TB/s).
// ---------------------------------------------------------------------------
__global__ __launch_bounds__(512) void k1_szt(
    const float* __restrict__ X, const u16* __restrict__ Wi_b,
    const u16* __restrict__ Wj_b, const u16* __restrict__ Ui_b,
    const float* __restrict__ mb1, const float* __restrict__ bp,
    u16* __restrict__ Sb, u8* __restrict__ Zf8, u16* __restrict__ T1)
{
  __shared__ u16 xt[16 * ND];   // 4 KB bf16 X tile, 16B-chunk XOR swizzle
  __shared__ u16 eS[16 * ND];   // 4 KB epilogue S
  __shared__ u8  eZ[16 * ND];   // 2 KB epilogue Z (fp8)
  __shared__ u16 eT[16 * ND];   // 4 KB epilogue T1
  const int tid = threadIdx.x, wid = tid >> 6, lane = tid & 63;
  const int r = lane & 15, q = lane >> 4;

  bf16x8 wiF[4], wjF[4], uiF[4];
  f32x4 mbF, bpF;
  {
    const int row = wid * 16 + r;
#pragma unroll
    for (int kk = 0; kk < 4; ++kk) {
      wiF[kk] = *(const bf16x8*)(Wi_b + row * ND + kk * 32 + q * 8);
      wjF[kk] = *(const bf16x8*)(Wj_b + row * ND + kk * 32 + q * 8);
      uiF[kk] = *(const bf16x8*)(Ui_b + row * ND + kk * 32 + q * 8);
    }
    mbF = *(const f32x4*)(mb1 + wid * 16 + q * 4);
    bpF = *(const f32x4*)(bp  + wid * 16 + q * 4);
  }

  // staging coords (X tile): thread -> (row rs, f32x4 chunk cs)
  const int rs = tid >> 5, cs = tid & 31;
  const int stb = rs * 256 + ((((cs >> 1) ^ (rs & 15)) << 4) | ((cs & 1) << 3));

  // epilogue write coords (lane: edge r, ch base wid*16+q*4)
  const int ewb = r * 256 + ((((wid * 2 + (q >> 1)) ^ (r & 15)) << 4) | ((q & 1) << 3));
  const int ezb = r * 128 + (((wid ^ (r & 7)) << 4) | (q * 4));
  // epilogue read coords: S/T (row, 8B chunk c8); Z (row, 4B chunk c4)
  const int erow = tid >> 5, c8 = tid & 31;
  const int erb = erow * 256 + ((((c8 >> 1) ^ (erow & 15)) << 4) | ((c8 & 1) << 3));
  const int zrb = erow * 128 + ((((c8 >> 2) ^ (erow & 7)) << 4) | ((c8 & 3) << 2));

  const long stride = gridDim.x;
  long t = blockIdx.x;
  if (t >= NTILES) return;

  f32x4 xr;
  auto gload = [&](long tt) {
    xr = *(const f32x4*)(X + (tt * 16 + rs) * ND + cs * 4);
  };
  auto stage = [&]() {
    bf16x4 b;
#pragma unroll
    for (int i = 0; i < 4; ++i) b[i] = (bf16_t)xr[i];
    *(bf16x4*)((char*)xt + stb) = b;
  };

  gload(t);
  stage();
  __syncthreads();

  for (; t < NTILES; t += stride) {
    const long tn = t + stride;
    if (tn < NTILES) gload(tn);

    bf16x8 xf[4];
#pragma unroll
    for (int kk = 0; kk < 4; ++kk)
      xf[kk] = *(const bf16x8*)((const char*)xt +
               r * 256 + (((kk * 4 + q) ^ (r & 15)) << 4));

    f32x4 aS = {0.f, 0.f, 0.f, 0.f};
    f32x4 aZ = {0.f, 0.f, 0.f, 0.f};
    f32x4 aT = {0.f, 0.f, 0.f, 0.f};
#pragma unroll
    for (int kk = 0; kk < 4; ++kk) {
      aS = __builtin_amdgcn_mfma_f32_16x16x32_bf16(wiF[kk], xf[kk], aS, 0, 0, 0);
      aZ = __builtin_amdgcn_mfma_f32_16x16x32_bf16(wjF[kk], xf[kk], aZ, 0, 0, 0);
      aT = __builtin_amdgcn_mfma_f32_16x16x32_bf16(uiF[kk], xf[kk], aT, 0, 0, 0);
    }

    bf16x4 pS, pT;
#pragma unroll
    for (int i = 0; i < 4; ++i) {
      pS[i] = (bf16_t)(aS[i] + mbF[i]);
      pT[i] = (bf16_t)(aT[i] + bpF[i]);
    }
    unsigned zpk = 0;
    zpk = __builtin_amdgcn_cvt_pk_fp8_f32(aZ[0], aZ[1], zpk, false);
    zpk = __builtin_amdgcn_cvt_pk_fp8_f32(aZ[2], aZ[3], zpk, true);
    *(bf16x4*)((char*)eS + ewb) = pS;
    *(bf16x4*)((char*)eT + ewb) = pT;
    *(unsigned*)((char*)eZ + ezb) = zpk;

    __syncthreads();   // (A): xt frag reads done; epilogue tiles visible

    // coalesced stores: thread -> contiguous chunk of one row
    {
      const long e = t * 16 + erow;
      const bf16x4 vS = *(const bf16x4*)((const char*)eS + erb);
      const bf16x4 vT = *(const bf16x4*)((const char*)eT + erb);
      const unsigned vZ = *(const unsigned*)((const char*)eZ + zrb);
      *(bf16x4*)(Sb + e * ND + c8 * 4) = vS;
      *(bf16x4*)(T1 + e * 256 + c8 * 4) = vT;
      *(unsigned*)(Zf8 + e * ND + c8 * 4) = vZ;
    }
    if (tn < NTILES) stage();   // write next X tile

    __syncthreads();   // (B): staged xt visible; epilogue reads done
  }
}

// ---------------------------------------------------------------------------
// k2: hbar[e] = (1/16) * sum_k relu(S[e] + Z[adj[e][k]]), Z in fp8 e4m3.
// Wave = 2 edges: half-wave per edge, lane covers 4 channels (1 dword fp8).
// (Round-7 version verbatim — control.)
// ---------------------------------------------------------------------------
__global__ __launch_bounds__(256) void k2_gather(
    const u8* __restrict__ Zf8, const u16* __restrict__ Sb,
    const int* __restrict__ adj, u16* __restrict__ Hb)
{
  const int tid = threadIdx.x, w4 = tid >> 6, lane = tid & 63;
  const int sub = lane >> 5, l = lane & 31;
  const long e = (long)blockIdx.x * 8 + w4 * 2 + sub;
  const int c0 = l * 4;

  const bf16x4 sv = *(const bf16x4*)(Sb + e * ND + c0);
  f32x4 s;
#pragma unroll
  for (int i = 0; i < 4; ++i) s[i] = (float)sv[i];

  const int myidx = adj[e * NK + (lane & 15)];

  f32x4 acc = {0.f, 0.f, 0.f, 0.f};
#pragma unroll
  for (int k = 0; k < NK; ++k) {
    const int n = __shfl(myidx, (lane & 32) + k);
    const unsigned zw = *(const unsigned*)(Zf8 + (long)n * ND + c0);
    const f32x2 zlo = __builtin_amdgcn_cvt_pk_f32_fp8(zw, false);
    const f32x2 zhi = __builtin_amdgcn_cvt_pk_f32_fp8(zw, true);
    f32x4 z;
    z[0] = zlo[0]; z[1] = zlo[1]; z[2] = zhi[0]; z[3] = zhi[1];
    f32x4 v = s + z;
#pragma unroll
    for (int i = 0; i < 4; ++i) v[i] = fmaxf(v[i], 0.f);
    acc += v;
  }

  bf16x4 hv;
#pragma unroll
  for (int i = 0; i < 4; ++i) hv[i] = (bf16_t)(acc[i] * 0.0625f);
  *(bf16x4*)(Hb + e * ND + c0) = hv;
}

// ---------------------------------------------------------------------------
// k3: u = relu(T1 + Hb@Wp^T); out = u@uW2^T + ub2. (Round-7 verbatim.)
// ---------------------------------------------------------------------------
__global__ __launch_bounds__(512) void k3_out(
    const u16* __restrict__ Hb, const u16* __restrict__ T1,
    const u16* __restrict__ Wp_b, const u16* __restrict__ W2_b,
    const float* __restrict__ ub2, float* __restrict__ out)
{
  __shared__ u16 ht[16 * ND];
  __shared__ u16 ut[16 * ND];
  const int tid = threadIdx.x, wid = tid >> 6, lane = tid & 63;
  const int r = lane & 15, q = lane >> 4;

  bf16x8 wpF[4], w2F[4];
  f32x4 ubF;
  {
    const int row = wid * 16 + r;
#pragma unroll
    for (int kk = 0; kk < 4; ++kk) {
      wpF[kk] = *(const bf16x8*)(Wp_b + row * ND + kk * 32 + q * 8);
      w2F[kk] = *(const bf16x8*)(W2_b + row * ND + kk * 32 + q * 8);
    }
    ubF = *(const f32x4*)(ub2 + wid * 16 + q * 4);
  }

  const int rs = tid >> 5, cs = tid & 31;
  const int stb = rs * 256 + ((((cs >> 1) ^ (rs & 15)) << 4) | ((cs & 1) << 3));

  const long stride = gridDim.x;
  long t = blockIdx.x;
  if (t >= NTILES) return;

  bf16x4 hr;
  auto gload = [&](long tt) {
    hr = *(const bf16x4*)(Hb + (tt * 16 + rs) * ND + cs * 4);
  };
  gload(t);
  *(bf16x4*)((char*)ht + stb) = hr;
  __syncthreads();

  for (; t < NTILES; t += stride) {
    const long tn = t + stride;
    if (tn < NTILES) gload(tn);

    bf16x8 hf[4];
#pragma unroll
    for (int kk = 0; kk < 4; ++kk)
      hf[kk] = *(const bf16x8*)((const char*)ht +
               r * 256 + (((kk * 4 + q) ^ (r & 15)) << 4));

    f32x4 acc;
    {
      const bf16x4 tv = *(const bf16x4*)(T1 + (t * 16 + r) * 256 + wid * 16 + q * 4);
#pragma unroll
      for (int i = 0; i < 4; ++i) acc[i] = (float)tv[i];
    }
#pragma unroll
    for (int kk = 0; kk < 4; ++kk)
      acc = __builtin_amdgcn_mfma_f32_16x16x32_bf16(wpF[kk], hf[kk], acc, 0, 0, 0);

    bf16x4 u;
#pragma unroll
    for (int i = 0; i < 4; ++i) u[i] = (bf16_t)fmaxf(acc[i], 0.f);
    const int uwb = r * 256 + ((((wid * 2 + (q >> 1)) ^ (r & 15)) << 4) | ((q & 1) << 3));

    __syncthreads();
    *(bf16x4*)((char*)ut + uwb) = u;
    if (tn < NTILES) *(bf16x4*)((char*)ht + stb) = hr;
    __syncthreads();

    bf16x8 uf[4];
#pragma unroll
    for (int kk = 0; kk < 4; ++kk)
      uf[kk] = *(const bf16x8*)((const char*)ut +
               r * 256 + (((kk * 4 + q) ^ (r & 15)) << 4));

    f32x4 o = {0.f, 0.f, 0.f, 0.f};
#pragma unroll
    for (int kk = 0; kk < 4; ++kk)
      o = __builtin_amdgcn_mfma_f32_16x16x32_bf16(w2F[kk], uf[kk], o, 0, 0, 0);
#pragma unroll
    for (int i = 0; i < 4; ++i) o[i] += ubF[i];
    *(f32x4*)(out + (t * 16 + r) * ND + wid * 16 + q * 4) = o;
  }
}

extern "C" void kernel_launch(void* const* d_in, const int* in_sizes, int n_in,
                              void* d_out, int out_size, void* d_ws, size_t ws_size,
                              hipStream_t stream)
{
  (void)in_sizes; (void)n_in; (void)out_size; (void)ws_size;
  const float* X   = (const float*)d_in[0];
  const int*   adj = (const int*)d_in[1];
  const float* mW1 = (const float*)d_in[2];
  const float* mb1 = (const float*)d_in[3];
  const float* mW2 = (const float*)d_in[4];
  const float* mb2 = (const float*)d_in[5];
  const float* uW1 = (const float*)d_in[6];
  const float* ub1 = (const float*)d_in[7];
  const float* uW2 = (const float*)d_in[8];
  const float* ub2 = (const float*)d_in[9];
  float* out = (float*)d_out;

  u16* ws16 = (u16*)d_ws;
  u16* Sb   = ws16;                              // E*D bf16 (25.6 MB)
  u16* Hb   = Sb + (size_t)NE * ND;              // E*D bf16 (25.6 MB)
  u8*  Zf8  = (u8*)(Hb + (size_t)NE * ND);       // E*D fp8  (12.8 MB)
  u16* Wi_b = (u16*)(Zf8 + (size_t)NE * ND);     // 128*128 bf16 each:
  u16* Wj_b = Wi_b + 128 * 128;
  u16* Ui_b = Wj_b + 128 * 128;
  u16* Wp_b = Ui_b + 128 * 128;
  u16* W2_b = Wp_b + 128 * 128;
  float* bp = (float*)(W2_b + 128 * 128);        // 128 f32
  u16* T1   = (u16*)d_out;                       // bf16 T1, stride 256, in out rows

  k_prep<<<128, 128, 0, stream>>>(mW1, uW1, uW2, mW2, ub1, mb2,
                                  Wi_b, Wj_b, Ui_b, Wp_b, W2_b, bp);

  k1_szt<<<1024, 512, 0, stream>>>(X, Wi_b, Wj_b, Ui_b, mb1, bp, Sb, Zf8, T1);

  k2_gather<<<NE / 8, 256, 0, stream>>>(Zf8, Sb, adj, Hb);

  k3_out<<<1024, 512, 0, stream>>>(Hb, T1, Wp_b, W2_b, ub2, out);
}